// Round 5
// baseline (7745.173 us; speedup 1.0000x reference)
//
#include <hip/hip_runtime.h>
#include <math.h>

// Problem constants (reference: B=512, S=512, D_IN=D_OUT=256, fp32)
#define S_LEN 512
#define B_SZ  512
#define D_DIM 256

// Fast, robust tanh: 1 - 2/(e^{2x}+1).
__device__ __forceinline__ float tanh_fast(float x) {
    float e = __expf(2.0f * x);
    return 1.0f - 2.0f / (e + 1.0f);
}

// ---------------------------------------------------------------------------
// Phase 1: Z[b,t,:] = x[b,t,:] @ Wx[t]   (Z written into d_out, fp32)
// v5: 32 batch rows/block (was 16) -> halves Wx re-read traffic through L2
// (16 blocks share each Wx[t], was 32). Per block: TCP 288 KB ~ 4600 cy vs
// VALU 8192 cy -> compute/memory balanced. grid (S, B/32), block 256 =
// 64 col-groups x 4 k-slices. Chunked 8-row reduce keeps red at 32 KB;
// LDS total 64 KB -> 2 blocks/CU (launch_bounds(256,2), VGPR cap 256 for
// the 128-VGPR accumulator file).
// ---------------------------------------------------------------------------
__global__ __launch_bounds__(256, 2) void phase1_xwx(const float* __restrict__ x,
                                                     const float* __restrict__ Wx,
                                                     float* __restrict__ Z) {
    const int t   = blockIdx.x;
    const int b0  = blockIdx.y * 32;
    const int tid = threadIdx.x;
    const int c4  = (tid & 63) * 4;   // column base (0..252)
    const int ks  = tid >> 6;         // k-slice 0..3 (wave-uniform)
    const int kbase = ks * 64;

    __shared__ float xs[32][D_DIM];      // 32 KB
    __shared__ float red[4][8][D_DIM];   // 32 KB (8-row chunks)

    // Stage x tile: 32 rows x 256 cols = 2048 float4s, 256 threads, 8 iters.
    #pragma unroll
    for (int i = 0; i < 8; ++i) {
        int idx = i * 256 + tid;         // [0, 2048)
        int r   = idx >> 6;              // row 0..31
        int cc  = (idx & 63) * 4;        // col base
        *(float4*)&xs[r][cc] =
            *(const float4*)(x + ((size_t)(b0 + r) * S_LEN + t) * D_DIM + cc);
    }
    __syncthreads();

    float4 acc[32];
    #pragma unroll
    for (int r = 0; r < 32; ++r) acc[r] = make_float4(0.f, 0.f, 0.f, 0.f);

    const float* wp = Wx + (size_t)t * D_DIM * D_DIM + c4;

    // 16 iters x 4 k. k ascending per output => stable summation order.
    // unroll 2 lets the compiler hoist the next group's w loads above the
    // current group's FMAs (512 FMA/iter hides the L2 round trip).
    #pragma unroll 2
    for (int k4 = 0; k4 < 16; ++k4) {
        const int k = kbase + k4 * 4;
        const float4 w0 = *(const float4*)(wp + (size_t)(k + 0) * D_DIM);
        const float4 w1 = *(const float4*)(wp + (size_t)(k + 1) * D_DIM);
        const float4 w2 = *(const float4*)(wp + (size_t)(k + 2) * D_DIM);
        const float4 w3 = *(const float4*)(wp + (size_t)(k + 3) * D_DIM);
        #pragma unroll
        for (int r = 0; r < 32; ++r) {
            const float4 xv = *(const float4*)&xs[r][k];  // wave-uniform bcast
            acc[r].x = fmaf(xv.x, w0.x, acc[r].x);
            acc[r].y = fmaf(xv.x, w0.y, acc[r].y);
            acc[r].z = fmaf(xv.x, w0.z, acc[r].z);
            acc[r].w = fmaf(xv.x, w0.w, acc[r].w);
            acc[r].x = fmaf(xv.y, w1.x, acc[r].x);
            acc[r].y = fmaf(xv.y, w1.y, acc[r].y);
            acc[r].z = fmaf(xv.y, w1.z, acc[r].z);
            acc[r].w = fmaf(xv.y, w1.w, acc[r].w);
            acc[r].x = fmaf(xv.z, w2.x, acc[r].x);
            acc[r].y = fmaf(xv.z, w2.y, acc[r].y);
            acc[r].z = fmaf(xv.z, w2.z, acc[r].z);
            acc[r].w = fmaf(xv.z, w2.w, acc[r].w);
            acc[r].x = fmaf(xv.w, w3.x, acc[r].x);
            acc[r].y = fmaf(xv.w, w3.y, acc[r].y);
            acc[r].z = fmaf(xv.w, w3.z, acc[r].z);
            acc[r].w = fmaf(xv.w, w3.w, acc[r].w);
        }
    }

    // Reduce + store in 4 chunks of 8 rows (red reused).
    #pragma unroll
    for (int ch = 0; ch < 4; ++ch) {
        #pragma unroll
        for (int rl = 0; rl < 8; ++rl)
            *(float4*)&red[ks][rl][c4] = acc[ch * 8 + rl];
        __syncthreads();
        #pragma unroll
        for (int i = 0; i < 2; ++i) {
            const int rl = ks * 2 + i;       // rows 0..7 across the 4 slices
            const int r  = ch * 8 + rl;
            const float4 s0 = *(const float4*)&red[0][rl][c4];
            const float4 s1 = *(const float4*)&red[1][rl][c4];
            const float4 s2 = *(const float4*)&red[2][rl][c4];
            const float4 s3 = *(const float4*)&red[3][rl][c4];
            float4 s;
            s.x = ((s0.x + s1.x) + s2.x) + s3.x;
            s.y = ((s0.y + s1.y) + s2.y) + s3.y;
            s.z = ((s0.z + s1.z) + s2.z) + s3.z;
            s.w = ((s0.w + s1.w) + s2.w) + s3.w;
            *(float4*)(Z + ((size_t)(b0 + r) * S_LEN + t) * D_DIM + c4) = s;
        }
        __syncthreads();
    }
}

// ---------------------------------------------------------------------------
// Phase 2: sequential scan. h_t = tanh(Z[:,t,:] + h_{t-1} @ Wh[t]).
//
// v5 (G=128 rebalance + real register w-stream):
//  * 128 blocks x 1024 threads, 4 batches/block. Every active CU reads the
//    full 256 KB Wh[t]/step (invariant); L2 traffic scales with block
//    count: G=256 (v4) -> 8 MB/step/XCD, L2-bound at 4.2 us/step measured.
//    G=128 balances L2 (16 CU/XCD x 256 KB = 4096 cy) against the per-CU
//    TCP floor (256 KB / 64 B/cy = 4096 cy) -> ~1.7 us/step floor.
//  * __launch_bounds__(1024, 4): VGPR cap 128. v4's VGPR_Count=32 proved
//    the compiler serialized the w-stream to chase occupancy; cap 128 lets
//    w[16] (64 VGPR) stay live -> 16 loads issued, progressive vmcnt
//    consumption.
//  * Reduce uses all 1024 threads (4 batches x 256 cols), no idle half.
//  * Summation order identical to v4 (16 slices x 16 k, z first).
// ---------------------------------------------------------------------------
__global__ __launch_bounds__(1024, 4) void phase2_scan(const float* __restrict__ Wh,
                                                       float* __restrict__ ZH) {
    const int g   = blockIdx.x;
    const int b0  = g * 4;
    const int tid = threadIdx.x;
    // k-loop mapping
    const int c4  = (tid & 63) * 4;   // column base (0..252)
    const int ks  = tid >> 6;         // k-slice 0..15 (wave-uniform)
    const int kbase = ks * 16;
    // reduce mapping: all 1024 threads, one (batch, col) each
    const int rm  = tid >> 8;         // batch 0..3 (wave-uniform)
    const int rc  = tid & 255;        // column 0..255

    __shared__ float h[4][D_DIM];          // 4 KB   hidden state
    __shared__ float red[16][4][D_DIM];    // 64 KB  partial-sum exchange

    for (int i = tid; i < 4 * D_DIM; i += 1024) ((float*)h)[i] = 0.0f;
    __syncthreads();

    float* zrow = ZH + ((size_t)(b0 + rm) * S_LEN) * D_DIM + rc;
    const float* wb = Wh + c4;

    for (int t = 0; t < S_LEN; ++t) {
        // Z prefetch (independent of h) -> hides under w-load/FMA phase.
        const float z = zrow[(size_t)t * D_DIM];

        // Full k-slice weight stream in registers: 16 x 1KB wave-loads in
        // flight (64 VGPR), FMAs consume with progressive vmcnt.
        const float* wt = wb + (size_t)t * D_DIM * D_DIM;
        float4 w[16];
        #pragma unroll
        for (int i = 0; i < 16; ++i)
            w[i] = *(const float4*)(wt + (size_t)(kbase + i) * D_DIM);

        float4 acc[4];
        #pragma unroll
        for (int m = 0; m < 4; ++m) acc[m] = make_float4(0.f, 0.f, 0.f, 0.f);

        #pragma unroll
        for (int q = 0; q < 4; ++q) {
            float4 hq[4];
            #pragma unroll
            for (int m = 0; m < 4; ++m)
                hq[m] = *(const float4*)&h[m][kbase + q * 4];  // uniform bcast
            #pragma unroll
            for (int j = 0; j < 4; ++j) {
                const float4 wj = w[q * 4 + j];
                #pragma unroll
                for (int m = 0; m < 4; ++m) {
                    const float hv = (j == 0) ? hq[m].x :
                                     (j == 1) ? hq[m].y :
                                     (j == 2) ? hq[m].z : hq[m].w;
                    acc[m].x = fmaf(hv, wj.x, acc[m].x);
                    acc[m].y = fmaf(hv, wj.y, acc[m].y);
                    acc[m].z = fmaf(hv, wj.z, acc[m].z);
                    acc[m].w = fmaf(hv, wj.w, acc[m].w);
                }
            }
        }

        // Publish partials (lanes write consecutive c4 -> conflict-free).
        #pragma unroll
        for (int m = 0; m < 4; ++m)
            *(float4*)&red[ks][m][c4] = acc[m];
        __syncthreads();

        // Balanced reduce: 1024 threads, one (batch, col) each; slices
        // ascending, z first (same order as v4 -> same rounding).
        float s = z;
        #pragma unroll
        for (int sl = 0; sl < 16; ++sl) s += red[sl][rm][rc];
        const float hv = tanh_fast(s);
        h[rm][rc] = hv;                      // next-step state
        zrow[(size_t)t * D_DIM] = hv;        // output over Z
        __syncthreads();
    }
}

// ---------------------------------------------------------------------------
extern "C" void kernel_launch(void* const* d_in, const int* in_sizes, int n_in,
                              void* d_out, int out_size, void* d_ws, size_t ws_size,
                              hipStream_t stream) {
    const float* x  = (const float*)d_in[0];   // [B, S, D_IN]
    const float* Wx = (const float*)d_in[1];   // [S, D_IN, D_OUT]
    const float* Wh = (const float*)d_in[2];   // [S, D_OUT, D_OUT]
    float* out = (float*)d_out;                // [B, S, D_OUT]

    // Phase 1: Z = batched x @ Wx  -> d_out (32 rows/block)
    phase1_xwx<<<dim3(S_LEN, B_SZ / 32), 256, 0, stream>>>(x, Wx, out);
    // Phase 2: sequential scan; 128 blocks x 4 batches (L2/TCP balanced)
    phase2_scan<<<dim3(B_SZ / 4), 1024, 0, stream>>>(Wh, out);
}

// Round 6
// 3971.638 us; speedup vs baseline: 1.9501x; 1.9501x over previous
//
#include <hip/hip_runtime.h>
#include <math.h>

// Problem constants (reference: B=512, S=512, D_IN=D_OUT=256, fp32)
#define S_LEN 512
#define B_SZ  512
#define D_DIM 256

// Fast, robust tanh: 1 - 2/(e^{2x}+1).
__device__ __forceinline__ float tanh_fast(float x) {
    float e = __expf(2.0f * x);
    return 1.0f - 2.0f / (e + 1.0f);
}

// ---------------------------------------------------------------------------
// Phase 1: Z[b,t,:] = x[b,t,:] @ Wx[t]   (Z written into d_out, fp32)
// grid (S, B/16), block 256 = 64 col-groups x 4 k-slices.
// Round-4 version restored verbatim (measured ~950 us, no spill).
// v5's 32-row variant spilled to scratch (22 GB/dispatch HBM traffic) —
// acc[32] float4 = 128 VGPR alone. 16 rows (acc[16] = 64 VGPR) fits.
// ---------------------------------------------------------------------------
__global__ __launch_bounds__(256, 2) void phase1_xwx(const float* __restrict__ x,
                                                     const float* __restrict__ Wx,
                                                     float* __restrict__ Z) {
    const int t   = blockIdx.x;
    const int b0  = blockIdx.y * 16;
    const int tid = threadIdx.x;
    const int c4  = (tid & 63) * 4;   // column base (0..252)
    const int ks  = tid >> 6;         // k-slice 0..3 (wave-uniform)
    const int kbase = ks * 64;

    __shared__ float xs[16][D_DIM];       // 16 KB
    __shared__ float red[4][16][D_DIM];   // 64 KB partial sums

    // Cooperative stage of the x tile: 16 rows x 256 cols = 1024 float4s.
    #pragma unroll
    for (int r4 = 0; r4 < 4; ++r4) {
        int idx = r4 * 256 + tid;        // [0, 1024)
        int r   = idx >> 6;              // row 0..15
        int cc  = (idx & 63) * 4;        // col base
        *(float4*)&xs[r][cc] =
            *(const float4*)(x + ((size_t)(b0 + r) * S_LEN + t) * D_DIM + cc);
    }
    __syncthreads();

    float4 acc[16];
    #pragma unroll
    for (int r = 0; r < 16; ++r) acc[r] = make_float4(0.f, 0.f, 0.f, 0.f);

    const float* wp = Wx + (size_t)t * D_DIM * D_DIM + c4;

    // 16 iters x 4 k. k ascending per output => stable summation order.
    #pragma unroll 2
    for (int k4 = 0; k4 < 16; ++k4) {
        const int k = kbase + k4 * 4;
        const float4 w0 = *(const float4*)(wp + (size_t)(k + 0) * D_DIM);
        const float4 w1 = *(const float4*)(wp + (size_t)(k + 1) * D_DIM);
        const float4 w2 = *(const float4*)(wp + (size_t)(k + 2) * D_DIM);
        const float4 w3 = *(const float4*)(wp + (size_t)(k + 3) * D_DIM);
        #pragma unroll
        for (int r = 0; r < 16; ++r) {
            const float4 xv = *(const float4*)&xs[r][k];  // wave-uniform bcast
            acc[r].x = fmaf(xv.x, w0.x, acc[r].x);
            acc[r].y = fmaf(xv.x, w0.y, acc[r].y);
            acc[r].z = fmaf(xv.x, w0.z, acc[r].z);
            acc[r].w = fmaf(xv.x, w0.w, acc[r].w);
            acc[r].x = fmaf(xv.y, w1.x, acc[r].x);
            acc[r].y = fmaf(xv.y, w1.y, acc[r].y);
            acc[r].z = fmaf(xv.y, w1.z, acc[r].z);
            acc[r].w = fmaf(xv.y, w1.w, acc[r].w);
            acc[r].x = fmaf(xv.z, w2.x, acc[r].x);
            acc[r].y = fmaf(xv.z, w2.y, acc[r].y);
            acc[r].z = fmaf(xv.z, w2.z, acc[r].z);
            acc[r].w = fmaf(xv.z, w2.w, acc[r].w);
            acc[r].x = fmaf(xv.w, w3.x, acc[r].x);
            acc[r].y = fmaf(xv.w, w3.y, acc[r].y);
            acc[r].z = fmaf(xv.w, w3.z, acc[r].z);
            acc[r].w = fmaf(xv.w, w3.w, acc[r].w);
        }
    }

    // Publish all 4 slices (lanes write consecutive c4 -> conflict-free).
    #pragma unroll
    for (int r = 0; r < 16; ++r)
        *(float4*)&red[ks][r][c4] = acc[r];
    __syncthreads();

    // Balanced reduce: each thread sums 4 slices for 4 (r, c4) outputs.
    #pragma unroll
    for (int i = 0; i < 4; ++i) {
        const int r = ks + i * 4;   // covers r 0..15 across ks
        const float4 s0 = *(const float4*)&red[0][r][c4];
        const float4 s1 = *(const float4*)&red[1][r][c4];
        const float4 s2 = *(const float4*)&red[2][r][c4];
        const float4 s3 = *(const float4*)&red[3][r][c4];
        float4 s;
        s.x = ((s0.x + s1.x) + s2.x) + s3.x;
        s.y = ((s0.y + s1.y) + s2.y) + s3.y;
        s.z = ((s0.z + s1.z) + s2.z) + s3.z;
        s.w = ((s0.w + s1.w) + s2.w) + s3.w;
        *(float4*)(Z + ((size_t)(b0 + r) * S_LEN + t) * D_DIM + c4) = s;
    }
}

// ---------------------------------------------------------------------------
// Phase 2: sequential scan. h_t = tanh(Z[:,t,:] + h_{t-1} @ Wh[t]).
//
// v6 (few fat waves; G=256 kept — measured best):
//  * G=128 (v5) regressed vs G=256 (v4): both latency-bound, so halving
//    active CUs lost. All 256 CUs stay active, 2 batches/block.
//  * 512 threads (8 waves, 2/SIMD), 8 k-slices x 32 k. launch_bounds(512,2)
//    -> VGPR cap 256 so the FULL per-step weight stream w[32] (128 VGPR,
//    32 KB) lives in registers. v4's VGPR_Count=32 proved the compiler
//    serialized the stream when left to chase occupancy; per-CU in-flight
//    bytes were tiny and L2 latency was exposed repeatedly. Now 256 KB/CU
//    (the whole step) is issued up-front, drained by TCP at ~64 B/cy
//    (~4096 cy) with FMAs consuming on progressive vmcnt.
//  * Global h-store deferred past barrier 2 (issued at top of next step):
//    its write-ack drains under the next load phase, not at the barrier.
//  * Plain __syncthreads(); no inline asm (v3 lesson).
// ---------------------------------------------------------------------------
__global__ __launch_bounds__(512, 2) void phase2_scan(const float* __restrict__ Wh,
                                                      float* __restrict__ ZH) {
    const int g   = blockIdx.x;
    const int b0  = g * 2;
    const int tid = threadIdx.x;
    // k-loop mapping
    const int c4  = (tid & 63) * 4;   // column base (0..252)
    const int ks  = tid >> 6;         // k-slice 0..7 (wave-uniform)
    const int kbase = ks * 32;
    // reduce mapping: all 512 threads, one (batch, col) each
    const int rm  = tid >> 8;         // batch 0..1 (wave-uniform)
    const int rc  = tid & 255;        // column 0..255

    __shared__ float h[2][D_DIM];        // 2 KB   hidden state
    __shared__ float red[8][2][D_DIM];   // 16 KB  partial-sum exchange

    for (int i = tid; i < 2 * D_DIM; i += 512) ((float*)h)[i] = 0.0f;
    __syncthreads();

    float* zrow = ZH + ((size_t)(b0 + rm) * S_LEN) * D_DIM + rc;
    const float* wb = Wh + c4;

    float hv_prev = 0.0f;

    for (int t = 0; t < S_LEN; ++t) {
        // Deferred output store of step t-1: same thread, different address;
        // overlaps this step's weight-load phase instead of stalling barrier 2.
        if (t > 0) zrow[(size_t)(t - 1) * D_DIM] = hv_prev;

        // Z prefetch (independent of h) -> consumed only after barrier 1.
        const float z = zrow[(size_t)t * D_DIM];

        // Entire step's weight slice in registers: 32 x 1KB wave-loads in
        // flight (128 VGPR), progressive vmcnt consumption by the FMAs.
        const float* wt = wb + (size_t)t * D_DIM * D_DIM;
        float4 w[32];
        #pragma unroll
        for (int i = 0; i < 32; ++i)
            w[i] = *(const float4*)(wt + (size_t)(kbase + i) * D_DIM);

        float4 acc0 = make_float4(0.f, 0.f, 0.f, 0.f);
        float4 acc1 = make_float4(0.f, 0.f, 0.f, 0.f);
        #pragma unroll
        for (int q = 0; q < 8; ++q) {
            const float4 ha = *(const float4*)&h[0][kbase + q * 4];  // bcast
            const float4 hb = *(const float4*)&h[1][kbase + q * 4];  // bcast
            #pragma unroll
            for (int j = 0; j < 4; ++j) {
                const float4 wj = w[q * 4 + j];
                const float hva = (j == 0) ? ha.x : (j == 1) ? ha.y :
                                  (j == 2) ? ha.z : ha.w;
                const float hvb = (j == 0) ? hb.x : (j == 1) ? hb.y :
                                  (j == 2) ? hb.z : hb.w;
                acc0.x = fmaf(hva, wj.x, acc0.x);
                acc0.y = fmaf(hva, wj.y, acc0.y);
                acc0.z = fmaf(hva, wj.z, acc0.z);
                acc0.w = fmaf(hva, wj.w, acc0.w);
                acc1.x = fmaf(hvb, wj.x, acc1.x);
                acc1.y = fmaf(hvb, wj.y, acc1.y);
                acc1.z = fmaf(hvb, wj.z, acc1.z);
                acc1.w = fmaf(hvb, wj.w, acc1.w);
            }
        }

        // Publish partials (lanes write consecutive c4 -> conflict-free).
        *(float4*)&red[ks][0][c4] = acc0;
        *(float4*)&red[ks][1][c4] = acc1;
        __syncthreads();

        // Balanced reduce: 512 threads, one (batch, col) each; slices
        // ascending (k ascending overall), z first.
        float s = z;
        #pragma unroll
        for (int sl = 0; sl < 8; ++sl) s += red[sl][rm][rc];
        const float hv = tanh_fast(s);
        h[rm][rc] = hv;          // next-step state (LDS only here)
        hv_prev = hv;            // global store deferred to next iteration
        __syncthreads();
    }
    // Final step's output store.
    zrow[(size_t)(S_LEN - 1) * D_DIM] = hv_prev;
}

// ---------------------------------------------------------------------------
extern "C" void kernel_launch(void* const* d_in, const int* in_sizes, int n_in,
                              void* d_out, int out_size, void* d_ws, size_t ws_size,
                              hipStream_t stream) {
    const float* x  = (const float*)d_in[0];   // [B, S, D_IN]
    const float* Wx = (const float*)d_in[1];   // [S, D_IN, D_OUT]
    const float* Wh = (const float*)d_in[2];   // [S, D_OUT, D_OUT]
    float* out = (float*)d_out;                // [B, S, D_OUT]

    // Phase 1: Z = batched x @ Wx  -> d_out (16 rows/block, round-4 version)
    phase1_xwx<<<dim3(S_LEN, B_SZ / 16), 256, 0, stream>>>(x, Wx, out);
    // Phase 2: sequential scan; 256 blocks x 2 batches, fat-wave w-stream
    phase2_scan<<<dim3(B_SZ / 2), 512, 0, stream>>>(Wh, out);
}